// Round 1
// baseline (81.701 us; speedup 1.0000x reference)
//
#include <hip/hip_runtime.h>

#define N 1024
#define H 64
#define E (N * (N - 1))   // 1047552

// Kernel 1: per-node halves of the first Linear.
//   A[i][h] = b1[h] + sum_k emb[i][k] * W1[k][h]       (top half of W1)
//   B[i][h] =         sum_k emb[i][k] * W1[H+k][h]     (bottom half of W1)
// blockDim = (64, 4): 4 nodes per block, one wave per node row.
__global__ __launch_bounds__(256) void precompute_ab(
    const float* __restrict__ emb, const float* __restrict__ W1,
    const float* __restrict__ b1, float* __restrict__ A, float* __restrict__ Bm)
{
    const int i = blockIdx.x * 4 + threadIdx.y;
    const int h = threadIdx.x;
    const float* er = emb + i * H;
    float a = b1[h];
    float b = 0.f;
#pragma unroll
    for (int k = 0; k < H; ++k) {
        const float ev = er[k];                 // uniform across lanes -> broadcast
        a = fmaf(ev, W1[k * H + h], a);         // coalesced across h
        b = fmaf(ev, W1[(H + k) * H + h], b);
    }
    A[i * H + h] = a;
    Bm[i * H + h] = b;
}

#define ITILE 4

// Kernel 2: each thread owns one j (B[j] held in 64 VGPRs), loops ITILE
// uniform i values (A-row + w2 are wave-uniform -> scalar/broadcast loads).
// Writes are coalesced: for fixed i, consecutive j -> consecutive e.
// ITILE=4 -> 1024 blocks -> 4 waves/SIMD for latency hiding.
__global__ __launch_bounds__(256) void edge_kernel(
    const float* __restrict__ A, const float* __restrict__ Bm,
    const float* __restrict__ W2, const float* __restrict__ b2,
    float* __restrict__ out)
{
    const int j  = blockIdx.x * 256 + threadIdx.x;  // gridDim.x = N/256
    const int i0 = blockIdx.y * ITILE;              // gridDim.y = N/ITILE

    float4 breg[16];
    const float4* bp = (const float4*)(Bm + j * H);
#pragma unroll
    for (int q = 0; q < 16; ++q) breg[q] = bp[q];

    // W2 is wave-uniform: force it into SGPRs so it costs 0 VGPRs.
    float w[64];
    const float* wp = W2;
#pragma unroll
    for (int q = 0; q < 64; ++q)
        w[q] = __uint_as_float(__builtin_amdgcn_readfirstlane(__float_as_uint(wp[q])));
    const float bias2 = __uint_as_float(__builtin_amdgcn_readfirstlane(__float_as_uint(b2[0])));

#pragma unroll
    for (int ii = 0; ii < ITILE; ++ii) {
        const int i = i0 + ii;
        const float4* ap = (const float4*)(A + i * H);  // uniform address
        float a0 = 0.f, a1 = 0.f, a2 = 0.f, a3 = 0.f;   // break FMA dep chain
#pragma unroll
        for (int q = 0; q < 16; ++q) {
            const float4 a = ap[q];
            const float4 b = breg[q];
            a0 = fmaf(fmaxf(a.x + b.x, 0.f), w[4 * q + 0], a0);
            a1 = fmaf(fmaxf(a.y + b.y, 0.f), w[4 * q + 1], a1);
            a2 = fmaf(fmaxf(a.z + b.z, 0.f), w[4 * q + 2], a2);
            a3 = fmaf(fmaxf(a.w + b.w, 0.f), w[4 * q + 3], a3);
        }
        const float x = (a0 + a1) + (a2 + a3) + bias2;
        const float s = 1.f / (1.f + __expf(-x));
        if (j != i) {
            const int e = i * (N - 1) + (j < i ? j : j - 1);
            out[e]         = (float)i;   // edge_index row 0
            out[E + e]     = (float)j;   // edge_index row 1
            out[2 * E + e] = s;          // edge_weights
        }
    }
}

extern "C" void kernel_launch(void* const* d_in, const int* in_sizes, int n_in,
                              void* d_out, int out_size, void* d_ws, size_t ws_size,
                              hipStream_t stream) {
    const float* emb = (const float*)d_in[0];   // [N, H]
    const float* W1  = (const float*)d_in[1];   // [2H, H]
    const float* b1  = (const float*)d_in[2];   // [H]
    const float* W2  = (const float*)d_in[3];   // [H, 1]
    const float* b2  = (const float*)d_in[4];   // [1]

    float* A  = (float*)d_ws;                   // [N, H]
    float* Bm = A + N * H;                      // [N, H]  (total 512 KB of ws)

    dim3 pgrid(N / 4);
    dim3 pblock(64, 4);
    precompute_ab<<<pgrid, pblock, 0, stream>>>(emb, W1, b1, A, Bm);

    dim3 grid(N / 256, N / ITILE);              // (4, 256) = 1024 blocks
    edge_kernel<<<grid, 256, 0, stream>>>(A, Bm, W2, b2, (float*)d_out);
}